// Round 7
// baseline (185.718 us; speedup 1.0000x reference)
//
#include <hip/hip_runtime.h>
#include <float.h>
#include <stdint.h>

#define EMB_DIM  300
#define MAX_LEN  128
#define HIDDEN   1000
#define NCLS     5
#define VOCAB_SZ 50000
#define KPAD     640     // 600 padded to 20*32
#define NPAD     1024    // 1000 padded to 16*64
#define EMBPAD   320     // 300 dims padded to 320 shorts = 640 B = 5 x 128 B lines

typedef float    f32x4  __attribute__((ext_vector_type(4)));
typedef __bf16   bf16x8 __attribute__((ext_vector_type(8)));
typedef unsigned short ushort8v __attribute__((ext_vector_type(8)));

__device__ __forceinline__ unsigned short f2bf(float f) {
    union { float f; uint32_t u; } v; v.f = f;
    uint32_t u = v.u;
    return (unsigned short)((u + 0x7FFFu + ((u >> 16) & 1u)) >> 16);   // RNE
}
__device__ __forceinline__ float bf2f(unsigned short h) {
    union { uint32_t u; float f; } v; v.u = ((uint32_t)h) << 16;
    return v.f;
}

// ---------------------------------------------------------------------------
// prep_weights: one dispatch for both weight preps.
//  blocks x<32:  transpose W1 [600][1000] f32 -> W1T [1024][640] bf16
//  blocks x==32: W2 [1000][5] f32 -> W2T [5][1024] bf16 (20 blocks * 256 = 5120)
// ---------------------------------------------------------------------------
__global__ __launch_bounds__(256) void prep_weights(
    const float* __restrict__ W1, unsigned short* __restrict__ Bt,
    const float* __restrict__ W2, unsigned short* __restrict__ W2t)
{
    if (blockIdx.x == 32) {
        const int i = blockIdx.y * 256 + threadIdx.x;    // [0, 5120)
        const int c = i >> 10, k = i & 1023;
        const float v = (k < HIDDEN) ? W2[(size_t)k * NCLS + c] : 0.f;
        W2t[(size_t)c * 1024 + k] = f2bf(v);
        return;
    }
    __shared__ float t[32][33];
    const int tx = threadIdx.x & 31, ty = threadIdx.x >> 5;   // 32 x 8
    const int n0 = blockIdx.x * 32, k0 = blockIdx.y * 32;
    #pragma unroll
    for (int i = 0; i < 4; ++i) {
        int k = k0 + ty + i * 8, n = n0 + tx;
        t[ty + i * 8][tx] = (k < 600 && n < HIDDEN) ? W1[(size_t)k * HIDDEN + n] : 0.f;
    }
    __syncthreads();
    #pragma unroll
    for (int i = 0; i < 4; ++i) {
        int n = n0 + ty + i * 8, k = k0 + tx;
        Bt[(size_t)n * KPAD + k] = f2bf(t[tx][ty + i * 8]);
    }
}

// ---------------------------------------------------------------------------
// convert_emb: emb [50000][300] f32 -> embb [50000][320] bf16 (zero-padded).
// ---------------------------------------------------------------------------
__global__ __launch_bounds__(256) void convert_emb(
    const float* __restrict__ emb, unsigned short* __restrict__ embb)
{
    const int i = blockIdx.x * 256 + threadIdx.x;     // chunk of 4 shorts
    const int total = VOCAB_SZ * (EMBPAD / 4);
    if (i >= total) return;
    const int v  = i / (EMBPAD / 4);
    const int ch = i - v * (EMBPAD / 4);
    ushort4 o = {0, 0, 0, 0};
    if (ch < 75) {
        const float4 f = *(const float4*)(emb + (size_t)v * EMB_DIM + ch * 4);
        o.x = f2bf(f.x); o.y = f2bf(f.y); o.z = f2bf(f.z); o.w = f2bf(f.w);
    }
    *(ushort4*)(embb + (size_t)v * EMBPAD + ch * 4) = o;
}

// ---------------------------------------------------------------------------
// pool_bf16: gather + masked avg/max over bf16 table -> rep bf16 [B][640].
// ---------------------------------------------------------------------------
__global__ __launch_bounds__(128) void pool_bf16(
    const int* __restrict__ x, const int* __restrict__ lengths,
    const unsigned short* __restrict__ embb, unsigned short* __restrict__ rep)
{
    const int b = blockIdx.x;
    const int t = threadIdx.x;

    __shared__ int sidx[MAX_LEN];
    sidx[t] = x[b * MAX_LEN + t];
    __syncthreads();

    unsigned short* rb = rep + (size_t)b * KPAD;

    if (t >= 75) {
        if (t < 85) {                      // zero pad cols 600..639
            ushort4 z = {0, 0, 0, 0};
            *(ushort4*)(rb + 600 + (t - 75) * 4) = z;
        }
        return;
    }

    int L = lengths[b];
    L = max(1, min(L, MAX_LEN));

    const int d = t * 4;
    float4 s  = {0.f, 0.f, 0.f, 0.f};
    float4 mx = {-FLT_MAX, -FLT_MAX, -FLT_MAX, -FLT_MAX};

    int i = 0;
    for (; i + 2 <= L; i += 2) {
        int i0 = max(0, min(sidx[i],     VOCAB_SZ - 1));
        int i1 = max(0, min(sidx[i + 1], VOCAB_SZ - 1));
        const ushort4 a = *(const ushort4*)(embb + (size_t)i0 * EMBPAD + d);
        const ushort4 c = *(const ushort4*)(embb + (size_t)i1 * EMBPAD + d);
        float a0 = bf2f(a.x), a1 = bf2f(a.y), a2 = bf2f(a.z), a3 = bf2f(a.w);
        float c0 = bf2f(c.x), c1 = bf2f(c.y), c2 = bf2f(c.z), c3 = bf2f(c.w);
        s.x += a0 + c0; s.y += a1 + c1; s.z += a2 + c2; s.w += a3 + c3;
        mx.x = fmaxf(mx.x, fmaxf(a0, c0)); mx.y = fmaxf(mx.y, fmaxf(a1, c1));
        mx.z = fmaxf(mx.z, fmaxf(a2, c2)); mx.w = fmaxf(mx.w, fmaxf(a3, c3));
    }
    if (i < L) {
        int i0 = max(0, min(sidx[i], VOCAB_SZ - 1));
        const ushort4 a = *(const ushort4*)(embb + (size_t)i0 * EMBPAD + d);
        float a0 = bf2f(a.x), a1 = bf2f(a.y), a2 = bf2f(a.z), a3 = bf2f(a.w);
        s.x += a0; s.y += a1; s.z += a2; s.w += a3;
        mx.x = fmaxf(mx.x, a0); mx.y = fmaxf(mx.y, a1);
        mx.z = fmaxf(mx.z, a2); mx.w = fmaxf(mx.w, a3);
    }

    const float inv = 1.0f / (float)L;
    ushort4 av, mv;
    av.x = f2bf(s.x * inv); av.y = f2bf(s.y * inv);
    av.z = f2bf(s.z * inv); av.w = f2bf(s.w * inv);
    mv.x = f2bf(mx.x); mv.y = f2bf(mx.y); mv.z = f2bf(mx.z); mv.w = f2bf(mx.w);
    *(ushort4*)(rb + d)       = av;     // avg -> [0,300)
    *(ushort4*)(rb + 300 + d) = mv;     // max -> [300,600)
}

// ---------------------------------------------------------------------------
// pool_f32 (fallback if ws too small for the bf16 table).
// ---------------------------------------------------------------------------
__global__ __launch_bounds__(128) void pool_f32(
    const int* __restrict__ x, const int* __restrict__ lengths,
    const float* __restrict__ emb, unsigned short* __restrict__ rep)
{
    const int b = blockIdx.x;
    const int t = threadIdx.x;

    __shared__ int sidx[MAX_LEN];
    sidx[t] = x[b * MAX_LEN + t];
    __syncthreads();

    unsigned short* rb = rep + (size_t)b * KPAD;

    if (t >= 75) {
        if (t < 85) {
            ushort4 z = {0, 0, 0, 0};
            *(ushort4*)(rb + 600 + (t - 75) * 4) = z;
        }
        return;
    }

    int L = lengths[b];
    L = max(1, min(L, MAX_LEN));

    const int d = t * 4;
    float4 s  = {0.f, 0.f, 0.f, 0.f};
    float4 mx = {-FLT_MAX, -FLT_MAX, -FLT_MAX, -FLT_MAX};

    for (int i = 0; i < L; ++i) {
        int idx = max(0, min(sidx[i], VOCAB_SZ - 1));
        const float4 v = *(const float4*)(emb + (size_t)idx * EMB_DIM + d);
        s.x += v.x; s.y += v.y; s.z += v.z; s.w += v.w;
        mx.x = fmaxf(mx.x, v.x); mx.y = fmaxf(mx.y, v.y);
        mx.z = fmaxf(mx.z, v.z); mx.w = fmaxf(mx.w, v.w);
    }

    const float inv = 1.0f / (float)L;
    ushort4 av, mv;
    av.x = f2bf(s.x * inv); av.y = f2bf(s.y * inv);
    av.z = f2bf(s.z * inv); av.w = f2bf(s.w * inv);
    mv.x = f2bf(mx.x); mv.y = f2bf(mx.y); mv.z = f2bf(mx.z); mv.w = f2bf(mx.w);
    *(ushort4*)(rb + d)       = av;
    *(ushort4*)(rb + 300 + d) = mv;
}

// ---------------------------------------------------------------------------
// gemm1_flat: hidden = relu(rep @ W1 + b1). NO LDS, NO barriers.
// MFMA fragments loaded straight from global (L2-resident operands):
//   A-frag: lane holds A[m=l&15][k=(l>>4)*8 + j] -> one bf16x8 load / frag
//   B-frag: same over n from W1T[n][k].
// Block = 64(M) x 64(N), 4 waves (2x2), wave tile 32x32 = 2x2 MFMAs.
// 1024 blocks; occupancy VGPR-limited only -> deep k-pipelining, zero
// barrier drains (round-6 theory: barrier-drain dominated the LDS version).
// ---------------------------------------------------------------------------
#define GBM 64
#define GBN 64

__global__ __launch_bounds__(256, 4) void gemm1_flat(
    const unsigned short* __restrict__ A,    // rep  [M][640] bf16
    const unsigned short* __restrict__ Bt,   // W1T  [1024][640] bf16
    const float* __restrict__ bias,          // b1 [1000]
    unsigned short* __restrict__ H,          // hidden [M][1000] bf16
    int M)
{
    const int tid  = threadIdx.x;
    const int wv   = tid >> 6;
    const int lane = tid & 63;
    const int q    = lane >> 4, r16 = lane & 15;

    const int bm = blockIdx.y * GBM + (wv & 1) * 32;    // wave m-origin
    const int bn = blockIdx.x * GBN + (wv >> 1) * 32;   // wave n-origin

    const unsigned short* a0 = A  + (size_t)(bm + r16) * KPAD + q * 8;
    const unsigned short* a1 = a0 + (size_t)16 * KPAD;
    const unsigned short* b0 = Bt + (size_t)(bn + r16) * KPAD + q * 8;
    const unsigned short* b1 = b0 + (size_t)16 * KPAD;

    f32x4 acc[2][2] = {};

    #pragma unroll 4
    for (int k0 = 0; k0 < KPAD; k0 += 32) {
        bf16x8 af0 = *(const bf16x8*)(a0 + k0);
        bf16x8 af1 = *(const bf16x8*)(a1 + k0);
        bf16x8 bf0 = *(const bf16x8*)(b0 + k0);
        bf16x8 bf1 = *(const bf16x8*)(b1 + k0);
        acc[0][0] = __builtin_amdgcn_mfma_f32_16x16x32_bf16(af0, bf0, acc[0][0], 0, 0, 0);
        acc[0][1] = __builtin_amdgcn_mfma_f32_16x16x32_bf16(af0, bf1, acc[0][1], 0, 0, 0);
        acc[1][0] = __builtin_amdgcn_mfma_f32_16x16x32_bf16(af1, bf0, acc[1][0], 0, 0, 0);
        acc[1][1] = __builtin_amdgcn_mfma_f32_16x16x32_bf16(af1, bf1, acc[1][1], 0, 0, 0);
    }

    // Epilogue. C/D layout: col = lane&15, row = (lane>>4)*4 + reg.
    #pragma unroll
    for (int nj = 0; nj < 2; ++nj) {
        int n = bn + nj * 16 + r16;
        if (n >= HIDDEN) continue;
        float bv = bias[n];
        #pragma unroll
        for (int mi = 0; mi < 2; ++mi) {
            #pragma unroll
            for (int r = 0; r < 4; ++r) {
                int m = bm + mi * 16 + q * 4 + r;
                float v = acc[mi][nj][r] + bv;
                H[(size_t)m * HIDDEN + n] = f2bf(fmaxf(v, 0.f));
            }
        }
    }
}

// ---------------------------------------------------------------------------
// gemm2: logits = hidden @ W2T + b2. 4 waves/block, one row per wave,
// coalesced 16B bf16 loads.
// ---------------------------------------------------------------------------
__global__ __launch_bounds__(256) void gemm2_kernel(
    const unsigned short* __restrict__ Hb,    // [B][1000] bf16
    const unsigned short* __restrict__ W2t,   // [5][1024] bf16
    const float* __restrict__ b2,             // [5]
    float* __restrict__ out)                  // [B][5]
{
    const int wv   = threadIdx.x >> 6;
    const int lane = threadIdx.x & 63;
    const int b    = blockIdx.x * 4 + wv;
    const unsigned short* hr = Hb + (size_t)b * HIDDEN;

    float acc[NCLS] = {0.f, 0.f, 0.f, 0.f, 0.f};
    #pragma unroll
    for (int c = 0; c < 2; ++c) {
        int k0 = c * 512 + lane * 8;
        if (k0 + 8 <= HIDDEN) {
            ushort8v hv = *(const ushort8v*)(hr + k0);
            ushort8v wv8[NCLS];
            #pragma unroll
            for (int cc = 0; cc < NCLS; ++cc)
                wv8[cc] = *(const ushort8v*)(W2t + cc * 1024 + k0);
            #pragma unroll
            for (int j = 0; j < 8; ++j) {
                float h = bf2f(hv[j]);
                #pragma unroll
                for (int cc = 0; cc < NCLS; ++cc)
                    acc[cc] += h * bf2f(wv8[cc][j]);
            }
        }
    }
    #pragma unroll
    for (int off = 32; off > 0; off >>= 1)
        #pragma unroll
        for (int cc = 0; cc < NCLS; ++cc)
            acc[cc] += __shfl_down(acc[cc], off, 64);

    if (lane == 0) {
        #pragma unroll
        for (int cc = 0; cc < NCLS; ++cc)
            out[(size_t)b * NCLS + cc] = acc[cc] + b2[cc];
    }
}

// ---------------------------------------------------------------------------
extern "C" void kernel_launch(void* const* d_in, const int* in_sizes, int n_in,
                              void* d_out, int out_size, void* d_ws, size_t ws_size,
                              hipStream_t stream)
{
    const int*   x       = (const int*)d_in[0];
    const int*   lengths = (const int*)d_in[1];
    const float* emb     = (const float*)d_in[2];
    const float* W1      = (const float*)d_in[3];
    const float* b1      = (const float*)d_in[4];
    const float* W2      = (const float*)d_in[5];
    const float* b2      = (const float*)d_in[6];
    float*       out     = (float*)d_out;

    const int B = in_sizes[1];               // 4096

    unsigned short* rep    = (unsigned short*)d_ws;           // [B][640]
    unsigned short* w1t    = rep + (size_t)B * KPAD;          // [1024][640]
    unsigned short* w2t    = w1t + (size_t)NPAD * KPAD;       // [5][1024]
    unsigned short* hidden = w2t + (size_t)NCLS * 1024;       // [B][1000]
    unsigned short* embb   = hidden + (size_t)B * HIDDEN;     // [50000][320]

    const size_t need = ((size_t)B * KPAD + (size_t)NPAD * KPAD + NCLS * 1024
                         + (size_t)B * HIDDEN + (size_t)VOCAB_SZ * EMBPAD) * 2;

    prep_weights<<<dim3(33, 20), 256, 0, stream>>>(W1, w1t, W2, w2t);

    if (ws_size >= need) {
        const int total = VOCAB_SZ * (EMBPAD / 4);
        convert_emb<<<(total + 255) / 256, 256, 0, stream>>>(emb, embb);
        pool_bf16<<<B, 128, 0, stream>>>(x, lengths, embb, rep);
    } else {
        pool_f32<<<B, 128, 0, stream>>>(x, lengths, emb, rep);
    }

    dim3 g1(NPAD / GBN, B / GBM);            // (16, 64) = 1024 blocks
    gemm1_flat<<<g1, 256, 0, stream>>>(rep, w1t, b1, hidden, B);

    gemm2_kernel<<<B / 4, 256, 0, stream>>>(hidden, w2t, b2, out);
}

// Round 9
// 160.361 us; speedup vs baseline: 1.1581x; 1.1581x over previous
//
#include <hip/hip_runtime.h>
#include <float.h>
#include <stdint.h>

#define EMB_DIM  300
#define MAX_LEN  128
#define HIDDEN   1000
#define NCLS     5
#define VOCAB_SZ 50000
#define KPAD     640     // 600 padded to 10*64
#define NPAD     1024    // 1000 padded to 16*64
#define EMBPAD   320     // 300 dims padded to 320 shorts = 640 B = 5 x 128 B lines

typedef float    f32x4  __attribute__((ext_vector_type(4)));
typedef __bf16   bf16x8 __attribute__((ext_vector_type(8)));
typedef unsigned short ushort8v __attribute__((ext_vector_type(8)));

#define CONV_BLOCKS ((VOCAB_SZ * (EMBPAD / 4) + 255) / 256)   // 15625

__device__ __forceinline__ unsigned short f2bf(float f) {
    union { float f; uint32_t u; } v; v.f = f;
    uint32_t u = v.u;
    return (unsigned short)((u + 0x7FFFu + ((u >> 16) & 1u)) >> 16);   // RNE
}
__device__ __forceinline__ float bf2f(unsigned short h) {
    union { uint32_t u; float f; } v; v.u = ((uint32_t)h) << 16;
    return v.f;
}

// ---------------------------------------------------------------------------
// prep_all: one dispatch for emb conversion + both weight preps.
//  blocks [0, CONV_BLOCKS):              emb f32 -> embb bf16 [50000][320]
//  blocks [CONV_BLOCKS, +640):           transpose W1 -> W1T bf16 [1024][640]
//  blocks [CONV_BLOCKS+640, +660):       W2 -> W2T bf16 [5][1024]
// ---------------------------------------------------------------------------
__global__ __launch_bounds__(256) void prep_all(
    const float* __restrict__ emb, unsigned short* __restrict__ embb,
    const float* __restrict__ W1, unsigned short* __restrict__ Bt,
    const float* __restrict__ W2, unsigned short* __restrict__ W2t)
{
    __shared__ float t[32][33];
    const int blk = blockIdx.x;

    if (blk < CONV_BLOCKS) {
        const int i = blk * 256 + threadIdx.x;     // chunk of 4 shorts
        if (i >= VOCAB_SZ * (EMBPAD / 4)) return;
        const int v  = i / (EMBPAD / 4);
        const int ch = i - v * (EMBPAD / 4);
        ushort4 o = {0, 0, 0, 0};
        if (ch < 75) {
            const float4 f = *(const float4*)(emb + (size_t)v * EMB_DIM + ch * 4);
            o.x = f2bf(f.x); o.y = f2bf(f.y); o.z = f2bf(f.z); o.w = f2bf(f.w);
        }
        *(ushort4*)(embb + (size_t)v * EMBPAD + ch * 4) = o;
        return;
    }
    const int pb = blk - CONV_BLOCKS;
    if (pb >= 640) {                               // W2T: 20 blocks
        const int i = (pb - 640) * 256 + threadIdx.x;    // [0, 5120)
        const int c = i >> 10, k = i & 1023;
        const float v = (k < HIDDEN) ? W2[(size_t)k * NCLS + c] : 0.f;
        W2t[(size_t)c * 1024 + k] = f2bf(v);
        return;
    }
    // W1 transpose: pb -> (px, py) in (32, 20)
    const int px = pb & 31, py = pb >> 5;
    const int tx = threadIdx.x & 31, ty = threadIdx.x >> 5;   // 32 x 8
    const int n0 = px * 32, k0 = py * 32;
    #pragma unroll
    for (int i = 0; i < 4; ++i) {
        int k = k0 + ty + i * 8, n = n0 + tx;
        t[ty + i * 8][tx] = (k < 600 && n < HIDDEN) ? W1[(size_t)k * HIDDEN + n] : 0.f;
    }
    __syncthreads();
    #pragma unroll
    for (int i = 0; i < 4; ++i) {
        int n = n0 + ty + i * 8, k = k0 + tx;
        Bt[(size_t)n * KPAD + k] = f2bf(t[tx][ty + i * 8]);
    }
}

// ---------------------------------------------------------------------------
// pool_bf16: gather + masked avg/max over bf16 table -> rep bf16 [B][640].
// ---------------------------------------------------------------------------
__global__ __launch_bounds__(128) void pool_bf16(
    const int* __restrict__ x, const int* __restrict__ lengths,
    const unsigned short* __restrict__ embb, unsigned short* __restrict__ rep)
{
    const int b = blockIdx.x;
    const int t = threadIdx.x;

    __shared__ int sidx[MAX_LEN];
    sidx[t] = x[b * MAX_LEN + t];
    __syncthreads();

    unsigned short* rb = rep + (size_t)b * KPAD;

    if (t >= 75) {
        if (t < 85) {                      // zero pad cols 600..639
            ushort4 z = {0, 0, 0, 0};
            *(ushort4*)(rb + 600 + (t - 75) * 4) = z;
        }
        return;
    }

    int L = lengths[b];
    L = max(1, min(L, MAX_LEN));

    const int d = t * 4;
    float4 s  = {0.f, 0.f, 0.f, 0.f};
    float4 mx = {-FLT_MAX, -FLT_MAX, -FLT_MAX, -FLT_MAX};

    int i = 0;
    for (; i + 2 <= L; i += 2) {
        int i0 = max(0, min(sidx[i],     VOCAB_SZ - 1));
        int i1 = max(0, min(sidx[i + 1], VOCAB_SZ - 1));
        const ushort4 a = *(const ushort4*)(embb + (size_t)i0 * EMBPAD + d);
        const ushort4 c = *(const ushort4*)(embb + (size_t)i1 * EMBPAD + d);
        float a0 = bf2f(a.x), a1 = bf2f(a.y), a2 = bf2f(a.z), a3 = bf2f(a.w);
        float c0 = bf2f(c.x), c1 = bf2f(c.y), c2 = bf2f(c.z), c3 = bf2f(c.w);
        s.x += a0 + c0; s.y += a1 + c1; s.z += a2 + c2; s.w += a3 + c3;
        mx.x = fmaxf(mx.x, fmaxf(a0, c0)); mx.y = fmaxf(mx.y, fmaxf(a1, c1));
        mx.z = fmaxf(mx.z, fmaxf(a2, c2)); mx.w = fmaxf(mx.w, fmaxf(a3, c3));
    }
    if (i < L) {
        int i0 = max(0, min(sidx[i], VOCAB_SZ - 1));
        const ushort4 a = *(const ushort4*)(embb + (size_t)i0 * EMBPAD + d);
        float a0 = bf2f(a.x), a1 = bf2f(a.y), a2 = bf2f(a.z), a3 = bf2f(a.w);
        s.x += a0; s.y += a1; s.z += a2; s.w += a3;
        mx.x = fmaxf(mx.x, a0); mx.y = fmaxf(mx.y, a1);
        mx.z = fmaxf(mx.z, a2); mx.w = fmaxf(mx.w, a3);
    }

    const float inv = 1.0f / (float)L;
    ushort4 av, mv;
    av.x = f2bf(s.x * inv); av.y = f2bf(s.y * inv);
    av.z = f2bf(s.z * inv); av.w = f2bf(s.w * inv);
    mv.x = f2bf(mx.x); mv.y = f2bf(mx.y); mv.z = f2bf(mx.z); mv.w = f2bf(mx.w);
    *(ushort4*)(rb + d)       = av;     // avg -> [0,300)
    *(ushort4*)(rb + 300 + d) = mv;     // max -> [300,600)
}

// ---------------------------------------------------------------------------
// pool_f32 (fallback if ws too small for the bf16 table).
// ---------------------------------------------------------------------------
__global__ __launch_bounds__(128) void pool_f32(
    const int* __restrict__ x, const int* __restrict__ lengths,
    const float* __restrict__ emb, unsigned short* __restrict__ rep)
{
    const int b = blockIdx.x;
    const int t = threadIdx.x;

    __shared__ int sidx[MAX_LEN];
    sidx[t] = x[b * MAX_LEN + t];
    __syncthreads();

    unsigned short* rb = rep + (size_t)b * KPAD;

    if (t >= 75) {
        if (t < 85) {
            ushort4 z = {0, 0, 0, 0};
            *(ushort4*)(rb + 600 + (t - 75) * 4) = z;
        }
        return;
    }

    int L = lengths[b];
    L = max(1, min(L, MAX_LEN));

    const int d = t * 4;
    float4 s  = {0.f, 0.f, 0.f, 0.f};
    float4 mx = {-FLT_MAX, -FLT_MAX, -FLT_MAX, -FLT_MAX};

    for (int i = 0; i < L; ++i) {
        int idx = max(0, min(sidx[i], VOCAB_SZ - 1));
        const float4 v = *(const float4*)(emb + (size_t)idx * EMB_DIM + d);
        s.x += v.x; s.y += v.y; s.z += v.z; s.w += v.w;
        mx.x = fmaxf(mx.x, v.x); mx.y = fmaxf(mx.y, v.y);
        mx.z = fmaxf(mx.z, v.z); mx.w = fmaxf(mx.w, v.w);
    }

    const float inv = 1.0f / (float)L;
    ushort4 av, mv;
    av.x = f2bf(s.x * inv); av.y = f2bf(s.y * inv);
    av.z = f2bf(s.z * inv); av.w = f2bf(s.w * inv);
    mv.x = f2bf(mx.x); mv.y = f2bf(mx.y); mv.z = f2bf(mx.z); mv.w = f2bf(mx.w);
    *(ushort4*)(rb + d)       = av;
    *(ushort4*)(rb + 300 + d) = mv;
}

// ---------------------------------------------------------------------------
// gemm1p: partials[nb] = relu(rep @ W1 + b1)[:, nb-slice] @ W2  (fused GEMM2)
// 64x64 tile, BK=64 (10 K-iters), LDS 32 KB dbuf, global_load_lds(16B),
// 4 waves (2x2), wave tile 32x32. Epilogue: p = relu(h)@W2T, butterfly-
// reduce over 16-lane n-groups, cross-wave combine in LDS, write
// partials[16][M][5] (no atomics).
// ---------------------------------------------------------------------------
#define BM 64
#define BN 64
#define BK 64

__global__ __launch_bounds__(256, 4) void gemm1p(
    const unsigned short* __restrict__ A,    // rep  [M][640] bf16
    const unsigned short* __restrict__ Bt,   // W1T  [1024][640] bf16
    const float* __restrict__ bias,          // b1 [1000]
    const unsigned short* __restrict__ W2t,  // [5][1024] bf16
    float* __restrict__ partials,            // [16][M][5]
    int M)
{
    __shared__ unsigned short As[2][BM * BK];   // 8 KB each buffer
    __shared__ unsigned short Bs[2][BN * BK];

    const int tid  = threadIdx.x;
    const int wv   = tid >> 6;
    const int lane = tid & 63;
    const int bm   = blockIdx.y * BM;
    const int bn   = blockIdx.x * BN;
    const int wr   = (wv & 1) * 32;
    const int wc   = (wv >> 1) * 32;

    f32x4 acc[2][2] = {};

    auto stage = [&](int buf, int k0) {
        // A tile: 64 rows x 128 B = 512 chunks -> 2 instr/wave, 8 rows each.
        #pragma unroll
        for (int j = 0; j < 2; ++j) {
            int ci  = (wv * 2 + j) * 64 + lane;
            int row = ci >> 3, c = ci & 7;
            const unsigned short* g = A + (size_t)(bm + row) * KPAD + k0 + c * 8;
            unsigned short* l = &As[buf][(wv * 2 + j) * 512];   // 1024 B / instr
            __builtin_amdgcn_global_load_lds(g, l, 16, 0, 0);
        }
        #pragma unroll
        for (int j = 0; j < 2; ++j) {
            int ci  = (wv * 2 + j) * 64 + lane;
            int row = ci >> 3, c = ci & 7;
            const unsigned short* g = Bt + (size_t)(bn + row) * KPAD + k0 + c * 8;
            unsigned short* l = &Bs[buf][(wv * 2 + j) * 512];
            __builtin_amdgcn_global_load_lds(g, l, 16, 0, 0);
        }
    };

    stage(0, 0);
    int cur = 0;
    const int q = lane >> 4, r16 = lane & 15;

    #pragma unroll 1
    for (int it = 0; it < KPAD / BK; ++it) {
        __syncthreads();
        if (it + 1 < KPAD / BK) stage(cur ^ 1, (it + 1) * BK);

        #pragma unroll
        for (int ks = 0; ks < BK; ks += 32) {
            bf16x8 af[2], bfr[2];
            #pragma unroll
            for (int mi = 0; mi < 2; ++mi)
                af[mi] = *(const bf16x8*)&As[cur][(wr + mi * 16 + r16) * BK + ks + q * 8];
            #pragma unroll
            for (int nj = 0; nj < 2; ++nj)
                bfr[nj] = *(const bf16x8*)&Bs[cur][(wc + nj * 16 + r16) * BK + ks + q * 8];
            #pragma unroll
            for (int mi = 0; mi < 2; ++mi)
                #pragma unroll
                for (int nj = 0; nj < 2; ++nj)
                    acc[mi][nj] = __builtin_amdgcn_mfma_f32_16x16x32_bf16(
                        af[mi], bfr[nj], acc[mi][nj], 0, 0, 0);
        }
        cur ^= 1;
    }

    // ---- fused epilogue: h -> partial logits ----
    // C/D layout: col(n) = r16, row(m) = q*4 + reg (+ mi*16).
    float bv[2], w2v[2][NCLS];
    #pragma unroll
    for (int nj = 0; nj < 2; ++nj) {
        int n = bn + wc + nj * 16 + r16;
        if (n < HIDDEN) {
            bv[nj] = bias[n];
            #pragma unroll
            for (int c = 0; c < NCLS; ++c) w2v[nj][c] = bf2f(W2t[c * 1024 + n]);
        } else {
            bv[nj] = 0.f;
            #pragma unroll
            for (int c = 0; c < NCLS; ++c) w2v[nj][c] = 0.f;
        }
    }

    __syncthreads();                     // LDS reuse: As becomes float scratch
    float* pl = (float*)As;              // [4][32][5] floats = 2560 B

    #pragma unroll
    for (int mi = 0; mi < 2; ++mi) {
        #pragma unroll
        for (int r = 0; r < 4; ++r) {
            float p[NCLS] = {0.f, 0.f, 0.f, 0.f, 0.f};
            #pragma unroll
            for (int nj = 0; nj < 2; ++nj) {
                float h = fmaxf(acc[mi][nj][r] + bv[nj], 0.f);
                #pragma unroll
                for (int c = 0; c < NCLS; ++c) p[c] += h * w2v[nj][c];
            }
            #pragma unroll
            for (int off = 1; off < 16; off <<= 1)
                #pragma unroll
                for (int c = 0; c < NCLS; ++c)
                    p[c] += __shfl_xor(p[c], off, 64);
            if (r16 == 0) {
                int lr = mi * 16 + q * 4 + r;          // 0..31 within wave tile
                #pragma unroll
                for (int c = 0; c < NCLS; ++c)
                    pl[(wv * 32 + lr) * NCLS + c] = p[c];
            }
        }
    }
    __syncthreads();

    // combine wave pairs (0+2 rows 0..31, 1+3 rows 32..63), write partials.
    // BM*NCLS = 320 > 256 threads -> strided loop (round-8 bug: plain
    // `if (tid < 320)` left rows 52..63 unwritten).
    for (int e = tid; e < BM * NCLS; e += 256) {
        int lr = e / NCLS, c = e - lr * NCLS;
        float v;
        if (lr < 32) v = pl[(0 * 32 + lr) * NCLS + c] + pl[(2 * 32 + lr) * NCLS + c];
        else         v = pl[(1 * 32 + lr - 32) * NCLS + c] + pl[(3 * 32 + lr - 32) * NCLS + c];
        partials[(size_t)blockIdx.x * M * NCLS + (size_t)(bm + lr) * NCLS + c] = v;
    }
}

// ---------------------------------------------------------------------------
// reduce_out: out[m][c] = b2[c] + sum_nb partials[nb][m][c]
// ---------------------------------------------------------------------------
__global__ __launch_bounds__(256) void reduce_out(
    const float* __restrict__ partials, const float* __restrict__ b2,
    float* __restrict__ out, int M)
{
    const int i = blockIdx.x * 256 + threadIdx.x;
    if (i >= M * NCLS) return;
    const int c = i % NCLS;
    float s = b2[c];
    #pragma unroll
    for (int nb = 0; nb < NPAD / BN; ++nb)
        s += partials[(size_t)nb * M * NCLS + i];
    out[i] = s;
}

// ---------------------------------------------------------------------------
extern "C" void kernel_launch(void* const* d_in, const int* in_sizes, int n_in,
                              void* d_out, int out_size, void* d_ws, size_t ws_size,
                              hipStream_t stream)
{
    const int*   x       = (const int*)d_in[0];
    const int*   lengths = (const int*)d_in[1];
    const float* emb     = (const float*)d_in[2];
    const float* W1      = (const float*)d_in[3];
    const float* b1      = (const float*)d_in[4];
    const float* W2      = (const float*)d_in[5];
    const float* b2      = (const float*)d_in[6];
    float*       out     = (float*)d_out;

    const int B = in_sizes[1];               // 4096

    unsigned short* rep      = (unsigned short*)d_ws;         // [B][640]
    unsigned short* w1t      = rep + (size_t)B * KPAD;        // [1024][640]
    unsigned short* w2t      = w1t + (size_t)NPAD * KPAD;     // [5][1024]
    unsigned short* embb     = w2t + (size_t)NCLS * 1024;     // [50000][320]
    float*          partials = (float*)(embb + (size_t)VOCAB_SZ * EMBPAD); // [16][B][5]

    const size_t need = ((size_t)B * KPAD + (size_t)NPAD * KPAD + NCLS * 1024
                         + (size_t)VOCAB_SZ * EMBPAD) * 2
                        + (size_t)(NPAD / BN) * B * NCLS * 4;

    prep_all<<<CONV_BLOCKS + 660, 256, 0, stream>>>(emb, embb, W1, w1t, W2, w2t);

    if (ws_size >= need) {
        pool_bf16<<<B, 128, 0, stream>>>(x, lengths, embb, rep);
    } else {
        pool_f32<<<B, 128, 0, stream>>>(x, lengths, emb, rep);
    }

    dim3 g1(NPAD / BN, B / BM);              // (16, 64) = 1024 blocks
    gemm1p<<<g1, 256, 0, stream>>>(rep, w1t, b1, w2t, partials, B);

    reduce_out<<<(B * NCLS + 255) / 256, 256, 0, stream>>>(partials, b2, out, B);
}